// Round 1
// baseline (849.406 us; speedup 1.0000x reference)
//
#include <hip/hip_runtime.h>

#define DID 128
#define NCLS 8

// ---------------------------------------------------------------- CSR build
__global__ void k_hist(const int* __restrict__ dst, int* __restrict__ deg, int E) {
  int e = blockIdx.x * 256 + threadIdx.x;
  if (e < E) atomicAdd(&deg[dst[e]], 1);
}

// exclusive scan, chunk=1024 per 256-thread block
__global__ void k_scan1(const int* __restrict__ deg, int* __restrict__ rp,
                        int* __restrict__ part, int n) {
  __shared__ int sd[256];
  int t = threadIdx.x;
  int base = blockIdx.x * 1024 + t * 4;
  int v0 = (base + 0 < n) ? deg[base + 0] : 0;
  int v1 = (base + 1 < n) ? deg[base + 1] : 0;
  int v2 = (base + 2 < n) ? deg[base + 2] : 0;
  int v3 = (base + 3 < n) ? deg[base + 3] : 0;
  int ts = v0 + v1 + v2 + v3;
  sd[t] = ts;
  __syncthreads();
  for (int off = 1; off < 256; off <<= 1) {
    int x = 0;
    if (t >= off) x = sd[t - off];
    __syncthreads();
    if (t >= off) sd[t] += x;
    __syncthreads();
  }
  int excl = sd[t] - ts;
  if (base + 0 < n) rp[base + 0] = excl;
  if (base + 1 < n) rp[base + 1] = excl + v0;
  if (base + 2 < n) rp[base + 2] = excl + v0 + v1;
  if (base + 3 < n) rp[base + 3] = excl + v0 + v1 + v2;
  if (t == 255) part[blockIdx.x] = sd[255];
}

__global__ void k_scan2(int* __restrict__ part, int nblk) {
  __shared__ int sd[1024];
  int t = threadIdx.x;
  int v = (t < nblk) ? part[t] : 0;
  sd[t] = v;
  __syncthreads();
  for (int off = 1; off < 1024; off <<= 1) {
    int x = 0;
    if (t >= off) x = sd[t - off];
    __syncthreads();
    if (t >= off) sd[t] += x;
    __syncthreads();
  }
  if (t < nblk) part[t] = sd[t] - v;  // exclusive block offsets
}

__global__ void k_scan3(int* __restrict__ rp, const int* __restrict__ part,
                        int n, int E) {
  int t = threadIdx.x;
  int add = part[blockIdx.x];
  int base = blockIdx.x * 1024 + t * 4;
#pragma unroll
  for (int i = 0; i < 4; ++i)
    if (base + i < n) rp[base + i] += add;
  if (blockIdx.x == 0 && t == 0) rp[n] = E;
}

__global__ void k_fill(const int* __restrict__ src, const int* __restrict__ dst,
                       const int* __restrict__ rp, int* __restrict__ fill,
                       int* __restrict__ col, int E) {
  int e = blockIdx.x * 256 + threadIdx.x;
  if (e < E) {
    int d = dst[e];
    int p = atomicAdd(&fill[d], 1);
    col[rp[d] + p] = src[e];
  }
}

// ---------------------------------------------------------------- fp32 GEMM
// O[n,128] = H[n,128] @ W[128,128]. 512 thr, 128-row tile, W staged in 32-k
// chunks. NOTE: H and O may alias (in-place safe: block reads only its own
// rows into LDS before its epilogue stores) -> no __restrict__ on H/O.
__device__ __forceinline__ float f4_get(const float4& v, int k) {
  switch (k & 3) {
    case 0: return v.x;
    case 1: return v.y;
    case 2: return v.z;
    default: return v.w;
  }
}

__global__ __launch_bounds__(512, 4) void k_gemm(const float* H,
                                                 const float* __restrict__ W,
                                                 float* O, int n) {
  __shared__ float hs[128 * 36];   // 128 rows x (32 k + 4 pad)
  __shared__ float wsh[32 * 128];  // 32 k-rows x 128 cols
  const int tid = threadIdx.x;
  const int tc = tid & 15;   // col group: cols 4*tc and 64+4*tc
  const int tr = tid >> 4;   // row group: rows 4*tr..4*tr+3
  const int rbase = blockIdx.x * 128;
  float acc[4][8];
#pragma unroll
  for (int r = 0; r < 4; ++r)
#pragma unroll
    for (int c = 0; c < 8; ++c) acc[r][c] = 0.f;

  const float4* H4 = (const float4*)H;
  const float4* W4 = (const float4*)W;

  for (int kc = 0; kc < 4; ++kc) {
    if (kc) __syncthreads();
#pragma unroll
    for (int i = 0; i < 2; ++i) {  // stage h rows (zero-fill OOB)
      int idx = i * 512 + tid;     // 0..1023
      int r = idx >> 3, c4 = idx & 7;
      int row = rbase + r;
      float4 v = make_float4(0.f, 0.f, 0.f, 0.f);
      if (row < n) v = H4[(size_t)row * 32 + kc * 8 + c4];
      *(float4*)&hs[r * 36 + c4 * 4] = v;
    }
#pragma unroll
    for (int i = 0; i < 2; ++i) {  // stage W chunk
      int idx = i * 512 + tid;
      int r = idx >> 5, c4 = idx & 31;
      *(float4*)&wsh[r * 128 + c4 * 4] = W4[(size_t)(kc * 32 + r) * 32 + c4];
    }
    __syncthreads();
#pragma unroll
    for (int k = 0; k < 32; k += 4) {
      float4 a0 = *(const float4*)&hs[(tr * 4 + 0) * 36 + k];
      float4 a1 = *(const float4*)&hs[(tr * 4 + 1) * 36 + k];
      float4 a2 = *(const float4*)&hs[(tr * 4 + 2) * 36 + k];
      float4 a3 = *(const float4*)&hs[(tr * 4 + 3) * 36 + k];
#pragma unroll
      for (int kk = 0; kk < 4; ++kk) {
        float4 w0 = *(const float4*)&wsh[(k + kk) * 128 + tc * 4];
        float4 w1 = *(const float4*)&wsh[(k + kk) * 128 + 64 + tc * 4];
#define ROWFMA(R, AV)                                                    \
  {                                                                      \
    float a_ = f4_get(AV, kk);                                           \
    acc[R][0] = fmaf(a_, w0.x, acc[R][0]);                               \
    acc[R][1] = fmaf(a_, w0.y, acc[R][1]);                               \
    acc[R][2] = fmaf(a_, w0.z, acc[R][2]);                               \
    acc[R][3] = fmaf(a_, w0.w, acc[R][3]);                               \
    acc[R][4] = fmaf(a_, w1.x, acc[R][4]);                               \
    acc[R][5] = fmaf(a_, w1.y, acc[R][5]);                               \
    acc[R][6] = fmaf(a_, w1.z, acc[R][6]);                               \
    acc[R][7] = fmaf(a_, w1.w, acc[R][7]);                               \
  }
        ROWFMA(0, a0)
        ROWFMA(1, a1)
        ROWFMA(2, a2)
        ROWFMA(3, a3)
#undef ROWFMA
      }
    }
  }
#pragma unroll
  for (int r = 0; r < 4; ++r) {
    int row = rbase + tr * 4 + r;
    if (row < n) {
      *(float4*)&O[(size_t)row * 128 + tc * 4] =
          make_float4(acc[r][0], acc[r][1], acc[r][2], acc[r][3]);
      *(float4*)&O[(size_t)row * 128 + 64 + tc * 4] =
          make_float4(acc[r][4], acc[r][5], acc[r][6], acc[r][7]);
    }
  }
}

// ------------------------------------------------- aggregation (pull, fused)
// ZB[i] = act(ZB[i] + (1/max(deg,1)) * sum_{e in CSR[i]} Y[col[e]] + bias)
// one wave per node, float2 per lane (64 lanes x 8B = full 512B row).
template <bool RELU>
__global__ __launch_bounds__(256, 8) void k_aggr(
    const float* __restrict__ Y, float* ZB, const int* __restrict__ rp,
    const int* __restrict__ col, const float* __restrict__ bias, int n) {
  int wid = (blockIdx.x * 256 + threadIdx.x) >> 6;
  int lane = threadIdx.x & 63;
  if (wid >= n) return;
  int s = rp[wid], e = rp[wid + 1];
  const float2* __restrict__ Y2 = (const float2*)Y;
  float ax = 0.f, ay = 0.f;
  int i = s;
  for (; i + 4 <= e; i += 4) {
    int c0 = col[i], c1 = col[i + 1], c2 = col[i + 2], c3 = col[i + 3];
    float2 v0 = Y2[(size_t)c0 * 64 + lane];
    float2 v1 = Y2[(size_t)c1 * 64 + lane];
    float2 v2 = Y2[(size_t)c2 * 64 + lane];
    float2 v3 = Y2[(size_t)c3 * 64 + lane];
    ax += v0.x + v1.x + v2.x + v3.x;
    ay += v0.y + v1.y + v2.y + v3.y;
  }
  for (; i < e; ++i) {
    int c = col[i];
    float2 v = Y2[(size_t)c * 64 + lane];
    ax += v.x;
    ay += v.y;
  }
  int deg = e - s;
  float scale = 1.0f / (float)(deg > 1 ? deg : 1);
  float2 z = ((const float2*)ZB)[(size_t)wid * 64 + lane];
  float2 bb = ((const float2*)bias)[lane];
  float ox = z.x + ax * scale + bb.x;
  float oy = z.y + ay * scale + bb.y;
  if (RELU) {
    ox = fmaxf(ox, 0.f);
    oy = fmaxf(oy, 0.f);
  }
  ((float2*)ZB)[(size_t)wid * 64 + lane] = make_float2(ox, oy);
}

// ---------------------------------------------------------------- pooling
__global__ void k_bounds(const int* __restrict__ gids, int* __restrict__ gs,
                         int n, int NG) {
  int g = threadIdx.x;
  if (g < NG) {
    int lo = 0, hi = n;
    while (lo < hi) {
      int m = (lo + hi) >> 1;
      if (gids[m] < g) lo = m + 1;
      else hi = m;
    }
    gs[g] = lo;
  } else if (g == NG) {
    gs[NG] = n;
  }
}

__global__ void k_pool(const float* __restrict__ H2, const int* __restrict__ gs,
                       float* __restrict__ gsum, int NG) {
  int g = blockIdx.x >> 2;
  int c = blockIdx.x & 3;
  int t = threadIdx.x;  // dim 0..127
  int s = gs[g], e = gs[g + 1];
  int cnt = e - s;
  int per = (cnt + 3) >> 2;
  int rs = s + c * per;
  int re = rs + per < e ? rs + per : e;
  float acc = 0.f;
  for (int r = rs; r < re; ++r) acc += H2[(size_t)r * DID + t];
  if (re > rs) atomicAdd(&gsum[g * DID + t], acc);
}

__global__ void k_head(const float* __restrict__ gsum,
                       const float* __restrict__ perm,
                       const float* __restrict__ Wc,
                       const float* __restrict__ bc,
                       const int* __restrict__ gs, float* __restrict__ out,
                       int NG) {
  int t = threadIdx.x;
  if (t >= NG * NCLS) return;
  int g = t >> 3, c = t & 7;
  int cnt = gs[g + 1] - gs[g];
  float inv = 1.0f / (float)(cnt > 1 ? cnt : 1);
  float acc = bc[c];
#pragma unroll 4
  for (int k = 0; k < DID; ++k)
    acc += gsum[g * DID + k] * inv * Wc[k * NCLS + c];
#pragma unroll 4
  for (int k = 0; k < DID; ++k)
    acc += perm[g * DID + k] * Wc[(DID + k) * NCLS + c];
  out[g * NCLS + c] = acc;
}

// ---------------------------------------------------------------- launch
extern "C" void kernel_launch(void* const* d_in, const int* in_sizes, int n_in,
                              void* d_out, int out_size, void* d_ws,
                              size_t ws_size, hipStream_t stream) {
  const float* h = (const float*)d_in[0];
  const float* perm = (const float*)d_in[1];
  const int* src = (const int*)d_in[2];
  const int* dst = (const int*)d_in[3];
  const int* gids = (const int*)d_in[4];
  const float* W1s = (const float*)d_in[5];
  const float* W1n = (const float*)d_in[6];
  const float* b1 = (const float*)d_in[7];
  const float* W2s = (const float*)d_in[8];
  const float* W2n = (const float*)d_in[9];
  const float* b2 = (const float*)d_in[10];
  const float* Wc = (const float*)d_in[11];
  const float* bc = (const float*)d_in[12];
  float* out = (float*)d_out;

  const int N = in_sizes[0] / DID;
  const int E = in_sizes[2];
  const int NG = in_sizes[1] / DID;

  char* w = (char*)d_ws;
  size_t off = 0;
  auto alloc = [&](size_t bytes) -> void* {
    off = (off + 511) & ~(size_t)511;
    void* p = w + off;
    off += bytes;
    return p;
  };
  int* deg = (int*)alloc((size_t)N * 4);
  int* fill = (int*)alloc((size_t)N * 4);
  float* gsum = (float*)alloc((size_t)NG * DID * 4);
  size_t zbytes = off;  // [deg|fill|gsum] region zeroed below
  int* rp = (int*)alloc((size_t)(N + 1) * 4);
  int* part = (int*)alloc(1024 * 4);
  int* gs = (int*)alloc((size_t)(NG + 1) * 4);
  int* col = (int*)alloc((size_t)E * 4);
  float* A = (float*)alloc((size_t)N * DID * 4);  // y = h @ W_neigh
  float* B = (float*)alloc((size_t)N * DID * 4);  // z / h1 / h2 (in place)

  hipMemsetAsync(d_ws, 0, zbytes, stream);

  const int nchunk = (N + 1023) / 1024;  // <= 1024 assumed
  const int egrid = (E + 255) / 256;
  const int ngb = (N + 127) / 128;
  const int nagg = (N + 3) / 4;

  // CSR by dst (reused for both layers)
  k_hist<<<egrid, 256, 0, stream>>>(dst, deg, E);
  k_scan1<<<nchunk, 256, 0, stream>>>(deg, rp, part, N);
  k_scan2<<<1, 1024, 0, stream>>>(part, nchunk);
  k_scan3<<<nchunk, 256, 0, stream>>>(rp, part, N, E);
  k_fill<<<egrid, 256, 0, stream>>>(src, dst, rp, fill, col, E);

  // layer 1
  k_gemm<<<ngb, 512, 0, stream>>>(h, W1n, A, N);   // y1
  k_gemm<<<ngb, 512, 0, stream>>>(h, W1s, B, N);   // z1
  k_aggr<true><<<nagg, 256, 0, stream>>>(A, B, rp, col, b1, N);  // B = h1

  // layer 2
  k_gemm<<<ngb, 512, 0, stream>>>(B, W2n, A, N);   // y2
  k_gemm<<<ngb, 512, 0, stream>>>(B, W2s, B, N);   // z2 (in-place, row-local)
  k_aggr<false><<<nagg, 256, 0, stream>>>(A, B, rp, col, b2, N);  // B = h2

  // readout
  k_bounds<<<1, 128, 0, stream>>>(gids, gs, N, NG);
  k_pool<<<NG * 4, 128, 0, stream>>>(B, gs, gsum, NG);
  k_head<<<1, 512, 0, stream>>>(gsum, perm, Wc, bc, gs, out, NG);
}

// Round 3
// 611.929 us; speedup vs baseline: 1.3881x; 1.3881x over previous
//
#include <hip/hip_runtime.h>

#define DID 128
#define NCLS 8

typedef __attribute__((ext_vector_type(8))) short bf16x8;
typedef __attribute__((ext_vector_type(4))) float f32x4;
typedef __attribute__((ext_vector_type(8))) unsigned short u16x8;

static __device__ __forceinline__ unsigned short f2bf(float f) {
  union { float f; unsigned int u; } x;
  x.f = f;
  unsigned int r = (x.u + 0x7fffu + ((x.u >> 16) & 1u)) >> 16;  // RNE
  return (unsigned short)r;
}
static __device__ __forceinline__ float bfhi(unsigned int v) {  // high bf16
  union { unsigned int u; float f; } x;
  x.u = v & 0xffff0000u;
  return x.f;
}
static __device__ __forceinline__ float bflo(unsigned int v) {  // low bf16
  union { unsigned int u; float f; } x;
  x.u = v << 16;
  return x.f;
}

// ---------------------------------------------------------------- CSR build
__global__ void k_hist(const int* __restrict__ dst, int* __restrict__ deg, int E) {
  int e = blockIdx.x * 256 + threadIdx.x;
  if (e < E) atomicAdd(&deg[dst[e]], 1);
}

__global__ void k_scan1(const int* __restrict__ deg, int* __restrict__ rp,
                        int* __restrict__ part, int n) {
  __shared__ int sd[256];
  int t = threadIdx.x;
  int base = blockIdx.x * 1024 + t * 4;
  int v0 = (base + 0 < n) ? deg[base + 0] : 0;
  int v1 = (base + 1 < n) ? deg[base + 1] : 0;
  int v2 = (base + 2 < n) ? deg[base + 2] : 0;
  int v3 = (base + 3 < n) ? deg[base + 3] : 0;
  int ts = v0 + v1 + v2 + v3;
  sd[t] = ts;
  __syncthreads();
  for (int off = 1; off < 256; off <<= 1) {
    int x = 0;
    if (t >= off) x = sd[t - off];
    __syncthreads();
    if (t >= off) sd[t] += x;
    __syncthreads();
  }
  int excl = sd[t] - ts;
  if (base + 0 < n) rp[base + 0] = excl;
  if (base + 1 < n) rp[base + 1] = excl + v0;
  if (base + 2 < n) rp[base + 2] = excl + v0 + v1;
  if (base + 3 < n) rp[base + 3] = excl + v0 + v1 + v2;
  if (t == 255) part[blockIdx.x] = sd[255];
}

__global__ void k_scan2(int* __restrict__ part, int nblk) {
  __shared__ int sd[1024];
  int t = threadIdx.x;
  int v = (t < nblk) ? part[t] : 0;
  sd[t] = v;
  __syncthreads();
  for (int off = 1; off < 1024; off <<= 1) {
    int x = 0;
    if (t >= off) x = sd[t - off];
    __syncthreads();
    if (t >= off) sd[t] += x;
    __syncthreads();
  }
  if (t < nblk) part[t] = sd[t] - v;
}

__global__ void k_scan3(int* __restrict__ rp, const int* __restrict__ part,
                        int n, int E) {
  int t = threadIdx.x;
  int add = part[blockIdx.x];
  int base = blockIdx.x * 1024 + t * 4;
#pragma unroll
  for (int i = 0; i < 4; ++i)
    if (base + i < n) rp[base + i] += add;
  if (blockIdx.x == 0 && t == 0) rp[n] = E;
}

__global__ void k_fill(const int* __restrict__ src, const int* __restrict__ dst,
                       const int* __restrict__ rp, int* __restrict__ fill,
                       int* __restrict__ col, int E) {
  int e = blockIdx.x * 256 + threadIdx.x;
  if (e < E) {
    int d = dst[e];
    int p = atomicAdd(&fill[d], 1);
    col[rp[d] + p] = src[e];
  }
}

// ---------------------------------------------------------- dtype conversion
// h fp32 -> bf16, 8 elements / thread
__global__ void k_h2b(const float* __restrict__ h, unsigned short* __restrict__ hb,
                      int total8) {
  int i = blockIdx.x * 256 + threadIdx.x;
  if (i >= total8) return;
  const float4* h4 = (const float4*)h;
  float4 a = h4[(size_t)i * 2];
  float4 b = h4[(size_t)i * 2 + 1];
  u16x8 o;
  o[0] = f2bf(a.x); o[1] = f2bf(a.y); o[2] = f2bf(a.z); o[3] = f2bf(a.w);
  o[4] = f2bf(b.x); o[5] = f2bf(b.y); o[6] = f2bf(b.z); o[7] = f2bf(b.w);
  *(u16x8*)(hb + (size_t)i * 8) = o;
}

// Pack W[128k x 128col] fp32 into MFMA B-fragment order (bf16), 4 matrices in
// one launch: Wp[((ct*4+kf)*64 + l)*8 + j] = W[k*128+col],
// col=ct*16+(l&15), k=kf*32+(l>>4)*8+j
__global__ void k_pack4(const float* __restrict__ W0, const float* __restrict__ W1,
                        const float* __restrict__ W2, const float* __restrict__ W3,
                        unsigned short* __restrict__ P0, unsigned short* __restrict__ P1,
                        unsigned short* __restrict__ P2, unsigned short* __restrict__ P3) {
  int gid = blockIdx.x * 256 + threadIdx.x;  // 0..65535
  int m = gid >> 14;                         // which matrix
  int idx = gid & 16383;
  int j = idx & 7;
  int l = (idx >> 3) & 63;
  int kf = (idx >> 9) & 3;
  int ct = idx >> 11;
  int colc = ct * 16 + (l & 15);
  int k = kf * 32 + (l >> 4) * 8 + j;
  const float* W = (m == 0) ? W0 : (m == 1) ? W1 : (m == 2) ? W2 : W3;
  unsigned short* P = (m == 0) ? P0 : (m == 1) ? P1 : (m == 2) ? P2 : P3;
  P[idx] = f2bf(W[k * 128 + colc]);
}

// ------------------------------------------------------- fused MFMA GEMM
// z[n,128] (fp32) = H@Ws ;  y[n,128] (bf16) = H@Wn.  H bf16 [n,128].
// 256 thr = 4 waves; block tile 128 rows; wave tile 32 rows x 128 cols x 2 mats.
__global__ __launch_bounds__(256, 2) void k_gemm2(
    const unsigned short* __restrict__ hb, const unsigned short* __restrict__ WpS,
    const unsigned short* __restrict__ WpN, float* __restrict__ z,
    unsigned short* __restrict__ yb, int n) {
  const int l = threadIdx.x & 63;
  const int w = threadIdx.x >> 6;
  const int rowW = blockIdx.x * 128 + w * 32;
  const int cl = l & 15;
  const int cg = l >> 4;

  bf16x8 A[2][4];
#pragma unroll
  for (int rt = 0; rt < 2; ++rt) {
    int row = rowW + rt * 16 + cl;
#pragma unroll
    for (int kf = 0; kf < 4; ++kf) {
      if (row < n)
        A[rt][kf] = *(const bf16x8*)(hb + (size_t)row * 128 + kf * 32 + cg * 8);
      else
        A[rt][kf] = (bf16x8){0, 0, 0, 0, 0, 0, 0, 0};
    }
  }

  f32x4 accS[2][8], accN[2][8];
#pragma unroll
  for (int rt = 0; rt < 2; ++rt)
#pragma unroll
    for (int ct = 0; ct < 8; ++ct) {
      accS[rt][ct] = (f32x4){0.f, 0.f, 0.f, 0.f};
      accN[rt][ct] = (f32x4){0.f, 0.f, 0.f, 0.f};
    }

#pragma unroll
  for (int ct = 0; ct < 8; ++ct) {
    bf16x8 BS[4], BN[4];
#pragma unroll
    for (int kf = 0; kf < 4; ++kf) {
      BS[kf] = *(const bf16x8*)(WpS + ((ct * 4 + kf) * 64 + l) * 8);
      BN[kf] = *(const bf16x8*)(WpN + ((ct * 4 + kf) * 64 + l) * 8);
    }
#pragma unroll
    for (int rt = 0; rt < 2; ++rt)
#pragma unroll
      for (int kf = 0; kf < 4; ++kf) {
        accS[rt][ct] =
            __builtin_amdgcn_mfma_f32_16x16x32_bf16(A[rt][kf], BS[kf], accS[rt][ct], 0, 0, 0);
        accN[rt][ct] =
            __builtin_amdgcn_mfma_f32_16x16x32_bf16(A[rt][kf], BN[kf], accN[rt][ct], 0, 0, 0);
      }
  }

#pragma unroll
  for (int rt = 0; rt < 2; ++rt)
#pragma unroll
    for (int ct = 0; ct < 8; ++ct) {
#pragma unroll
      for (int r = 0; r < 4; ++r) {
        int row = rowW + rt * 16 + cg * 4 + r;
        if (row < n) {
          int colc = ct * 16 + cl;
          z[(size_t)row * 128 + colc] = accS[rt][ct][r];
          yb[(size_t)row * 128 + colc] = f2bf(accN[rt][ct][r]);
        }
      }
    }
}

// ------------------------------------------------- aggregation (pull, fused)
// out[i] = act(Z[i] + mean_{e in CSR[i]} Ybf16[col[e]] + bias)
// one wave/node; lane covers dims 2*lane, 2*lane+1 (4B bf16 pair per gather).
// OUTMODE 1: relu + bf16 out ; OUTMODE 0: fp32 out (may alias Z, row-local).
template <int OUTMODE>
__global__ __launch_bounds__(256, 8) void k_aggr2(
    const unsigned int* __restrict__ Y, const float* Z,
    const int* __restrict__ rp, const int* __restrict__ col,
    const float* __restrict__ bias, void* outp, int n) {
  int wid = (blockIdx.x * 256 + threadIdx.x) >> 6;
  int lane = threadIdx.x & 63;
  if (wid >= n) return;
  int s = rp[wid], e = rp[wid + 1];
  float ax = 0.f, ay = 0.f;
  int i = s;
  for (; i + 4 <= e; i += 4) {
    int c0 = col[i], c1 = col[i + 1], c2 = col[i + 2], c3 = col[i + 3];
    unsigned int v0 = Y[(size_t)c0 * 64 + lane];
    unsigned int v1 = Y[(size_t)c1 * 64 + lane];
    unsigned int v2 = Y[(size_t)c2 * 64 + lane];
    unsigned int v3 = Y[(size_t)c3 * 64 + lane];
    ax += bflo(v0) + bflo(v1) + bflo(v2) + bflo(v3);
    ay += bfhi(v0) + bfhi(v1) + bfhi(v2) + bfhi(v3);
  }
  for (; i < e; ++i) {
    unsigned int v = Y[(size_t)col[i] * 64 + lane];
    ax += bflo(v);
    ay += bfhi(v);
  }
  int deg = e - s;
  float scale = 1.0f / (float)(deg > 1 ? deg : 1);
  float2 zv = ((const float2*)Z)[(size_t)wid * 64 + lane];
  float2 bb = ((const float2*)bias)[lane];
  float ox = zv.x + ax * scale + bb.x;
  float oy = zv.y + ay * scale + bb.y;
  if (OUTMODE == 1) {
    ox = fmaxf(ox, 0.f);
    oy = fmaxf(oy, 0.f);
    unsigned int packed = (unsigned int)f2bf(ox) | ((unsigned int)f2bf(oy) << 16);
    ((unsigned int*)outp)[(size_t)wid * 64 + lane] = packed;
  } else {
    ((float2*)outp)[(size_t)wid * 64 + lane] = make_float2(ox, oy);
  }
}

// ---------------------------------------------------------------- pooling
__global__ void k_bounds(const int* __restrict__ gids, int* __restrict__ gs,
                         int n, int NG) {
  int g = threadIdx.x;
  if (g < NG) {
    int lo = 0, hi = n;
    while (lo < hi) {
      int m = (lo + hi) >> 1;
      if (gids[m] < g) lo = m + 1;
      else hi = m;
    }
    gs[g] = lo;
  } else if (g == NG) {
    gs[NG] = n;
  }
}

__global__ void k_pool(const float* __restrict__ H2, const int* __restrict__ gs,
                       float* __restrict__ gsum, int NG) {
  int g = blockIdx.x >> 2;
  int c = blockIdx.x & 3;
  int t = threadIdx.x;
  int s = gs[g], e = gs[g + 1];
  int cnt = e - s;
  int per = (cnt + 3) >> 2;
  int rs = s + c * per;
  int re = rs + per < e ? rs + per : e;
  float acc = 0.f;
  for (int r = rs; r < re; ++r) acc += H2[(size_t)r * DID + t];
  if (re > rs) atomicAdd(&gsum[g * DID + t], acc);
}

__global__ void k_head(const float* __restrict__ gsum,
                       const float* __restrict__ perm,
                       const float* __restrict__ Wc,
                       const float* __restrict__ bc,
                       const int* __restrict__ gs, float* __restrict__ out,
                       int NG) {
  int t = threadIdx.x;
  if (t >= NG * NCLS) return;
  int g = t >> 3, c = t & 7;
  int cnt = gs[g + 1] - gs[g];
  float inv = 1.0f / (float)(cnt > 1 ? cnt : 1);
  float acc = bc[c];
#pragma unroll 4
  for (int k = 0; k < DID; ++k)
    acc += gsum[g * DID + k] * inv * Wc[k * NCLS + c];
#pragma unroll 4
  for (int k = 0; k < DID; ++k)
    acc += perm[g * DID + k] * Wc[(DID + k) * NCLS + c];
  out[g * NCLS + c] = acc;
}

// ---------------------------------------------------------------- launch
extern "C" void kernel_launch(void* const* d_in, const int* in_sizes, int n_in,
                              void* d_out, int out_size, void* d_ws,
                              size_t ws_size, hipStream_t stream) {
  const float* h = (const float*)d_in[0];
  const float* perm = (const float*)d_in[1];
  const int* src = (const int*)d_in[2];
  const int* dst = (const int*)d_in[3];
  const int* gids = (const int*)d_in[4];
  const float* W1s = (const float*)d_in[5];
  const float* W1n = (const float*)d_in[6];
  const float* b1 = (const float*)d_in[7];
  const float* W2s = (const float*)d_in[8];
  const float* W2n = (const float*)d_in[9];
  const float* b2 = (const float*)d_in[10];
  const float* Wc = (const float*)d_in[11];
  const float* bc = (const float*)d_in[12];
  float* out = (float*)d_out;

  const int N = in_sizes[0] / DID;
  const int E = in_sizes[2];
  const int NG = in_sizes[1] / DID;

  char* w = (char*)d_ws;
  size_t off = 0;
  auto alloc = [&](size_t bytes) -> void* {
    off = (off + 511) & ~(size_t)511;
    void* p = w + off;
    off += bytes;
    return p;
  };
  int* deg = (int*)alloc((size_t)N * 4);
  int* fill = (int*)alloc((size_t)N * 4);
  float* gsum = (float*)alloc((size_t)NG * DID * 4);
  size_t zbytes = off;  // [deg|fill|gsum] zeroed below
  int* rp = (int*)alloc((size_t)(N + 1) * 4);
  int* part = (int*)alloc(1024 * 4);
  int* gs = (int*)alloc((size_t)(NG + 1) * 4);
  int* col = (int*)alloc((size_t)E * 4);
  unsigned short* hb = (unsigned short*)alloc((size_t)N * DID * 2);  // h bf16; reused as h1 bf16
  unsigned short* yb = (unsigned short*)alloc((size_t)N * DID * 2);  // y bf16 (both layers)
  float* z = (float*)alloc((size_t)N * DID * 4);                     // z fp32; h2 in-place
  unsigned short* Wp1s = (unsigned short*)alloc(128 * 128 * 2);
  unsigned short* Wp1n = (unsigned short*)alloc(128 * 128 * 2);
  unsigned short* Wp2s = (unsigned short*)alloc(128 * 128 * 2);
  unsigned short* Wp2n = (unsigned short*)alloc(128 * 128 * 2);

  hipMemsetAsync(d_ws, 0, zbytes, stream);

  const int nchunk = (N + 1023) / 1024;
  const int egrid = (E + 255) / 256;
  const int ngb = (N + 127) / 128;
  const int nagg = (N + 3) / 4;
  const int ncvt = ((N * DID / 8) + 255) / 256;

  // CSR by dst (reused for both layers)
  k_hist<<<egrid, 256, 0, stream>>>(dst, deg, E);
  k_scan1<<<nchunk, 256, 0, stream>>>(deg, rp, part, N);
  k_scan2<<<1, 1024, 0, stream>>>(part, nchunk);
  k_scan3<<<nchunk, 256, 0, stream>>>(rp, part, N, E);
  k_fill<<<egrid, 256, 0, stream>>>(src, dst, rp, fill, col, E);

  // dtype prep
  k_h2b<<<ncvt, 256, 0, stream>>>(h, hb, N * DID / 8);
  k_pack4<<<256, 256, 0, stream>>>(W1s, W1n, W2s, W2n, Wp1s, Wp1n, Wp2s, Wp2n);

  // layer 1: z=h@W1s (f32), yb=h@W1n (bf16); aggr -> h1 bf16 (into hb)
  k_gemm2<<<ngb, 256, 0, stream>>>(hb, Wp1s, Wp1n, z, yb, N);
  k_aggr2<1><<<nagg, 256, 0, stream>>>((const unsigned int*)yb, z, rp, col, b1,
                                       (void*)hb, N);

  // layer 2: z=h1@W2s, yb=h1@W2n; aggr -> h2 fp32 (in-place in z)
  k_gemm2<<<ngb, 256, 0, stream>>>(hb, Wp2s, Wp2n, z, yb, N);
  k_aggr2<0><<<nagg, 256, 0, stream>>>((const unsigned int*)yb, z, rp, col, b2,
                                       (void*)z, N);

  // readout
  k_bounds<<<1, 128, 0, stream>>>(gids, gs, N, NG);
  k_pool<<<NG * 4, 128, 0, stream>>>(z, gs, gsum, NG);
  k_head<<<1, 512, 0, stream>>>(gsum, perm, Wc, bc, gs, out, NG);
}

// Round 4
// 499.604 us; speedup vs baseline: 1.7002x; 1.2248x over previous
//
#include <hip/hip_runtime.h>

#define DID 128
#define NCLS 8
#define NPB 512        // nodes per bucket (power of 2)
#define NPB_SHIFT 9
#define NBLK 512       // blocks in edge-partition kernels
#define CAP 12288      // col staging capacity per bucket (mean 8192 + 45 sigma)

typedef __attribute__((ext_vector_type(8))) short bf16x8;
typedef __attribute__((ext_vector_type(4))) float f32x4;
typedef __attribute__((ext_vector_type(8))) unsigned short u16x8;

static __device__ __forceinline__ unsigned short f2bf(float f) {
  union { float f; unsigned int u; } x;
  x.f = f;
  unsigned int r = (x.u + 0x7fffu + ((x.u >> 16) & 1u)) >> 16;  // RNE
  return (unsigned short)r;
}
static __device__ __forceinline__ float bfhi(unsigned int v) {
  union { unsigned int u; float f; } x;
  x.u = v & 0xffff0000u;
  return x.f;
}
static __device__ __forceinline__ float bflo(unsigned int v) {
  union { unsigned int u; float f; } x;
  x.u = v << 16;
  return x.f;
}

// ------------------------------------------------- bucketed CSR: pass A hist
// per-block LDS histogram over buckets -> hist[bucket*NBLK + block]
__global__ __launch_bounds__(256) void kB_hist(const int* __restrict__ dst,
                                               int* __restrict__ hist, int E,
                                               int nbuk) {
  __shared__ int c[256];
  int tid = threadIdx.x;
  for (int i = tid; i < nbuk; i += 256) c[i] = 0;
  __syncthreads();
  int epb = (E + NBLK - 1) / NBLK;
  int e0 = blockIdx.x * epb;
  int e1 = min(E, e0 + epb);
  for (int e = e0 + tid; e < e1; e += 256)
    atomicAdd(&c[dst[e] >> NPB_SHIFT], 1);
  __syncthreads();
  for (int i = tid; i < nbuk; i += 256)
    hist[(size_t)i * NBLK + blockIdx.x] = c[i];
}

// generic exclusive scan chain (1024 elems / 256-thr block)
__global__ void k_scan1(const int* __restrict__ deg, int* __restrict__ rp,
                        int* __restrict__ part, int n) {
  __shared__ int sd[256];
  int t = threadIdx.x;
  int base = blockIdx.x * 1024 + t * 4;
  int v0 = (base + 0 < n) ? deg[base + 0] : 0;
  int v1 = (base + 1 < n) ? deg[base + 1] : 0;
  int v2 = (base + 2 < n) ? deg[base + 2] : 0;
  int v3 = (base + 3 < n) ? deg[base + 3] : 0;
  int ts = v0 + v1 + v2 + v3;
  sd[t] = ts;
  __syncthreads();
  for (int off = 1; off < 256; off <<= 1) {
    int x = 0;
    if (t >= off) x = sd[t - off];
    __syncthreads();
    if (t >= off) sd[t] += x;
    __syncthreads();
  }
  int excl = sd[t] - ts;
  if (base + 0 < n) rp[base + 0] = excl;
  if (base + 1 < n) rp[base + 1] = excl + v0;
  if (base + 2 < n) rp[base + 2] = excl + v0 + v1;
  if (base + 3 < n) rp[base + 3] = excl + v0 + v1 + v2;
  if (t == 255) part[blockIdx.x] = sd[255];
}

__global__ void k_scan2(int* __restrict__ part, int nblk) {
  __shared__ int sd[1024];
  int t = threadIdx.x;
  int v = (t < nblk) ? part[t] : 0;
  sd[t] = v;
  __syncthreads();
  for (int off = 1; off < 1024; off <<= 1) {
    int x = 0;
    if (t >= off) x = sd[t - off];
    __syncthreads();
    if (t >= off) sd[t] += x;
    __syncthreads();
  }
  if (t < nblk) part[t] = sd[t] - v;
}

__global__ void k_scan3(int* __restrict__ rp, const int* __restrict__ part,
                        int n, int E) {
  int t = threadIdx.x;
  int add = part[blockIdx.x];
  int base = blockIdx.x * 1024 + t * 4;
#pragma unroll
  for (int i = 0; i < 4; ++i)
    if (base + i < n) rp[base + i] += add;
  if (blockIdx.x == 0 && t == 0) rp[n] = E;
}

// -------------------------------------------- bucketed CSR: pass A scatter
// each (bucket,block) pair owns a private contiguous region of pairs[]
__global__ __launch_bounds__(256) void kB_scat(const int* __restrict__ src,
                                               const int* __restrict__ dst,
                                               const int* __restrict__ off,
                                               unsigned long long* __restrict__ pairs,
                                               int E, int nbuk) {
  __shared__ int cur[256];
  int tid = threadIdx.x;
  for (int i = tid; i < nbuk; i += 256)
    cur[i] = off[(size_t)i * NBLK + blockIdx.x];
  __syncthreads();
  int epb = (E + NBLK - 1) / NBLK;
  int e0 = blockIdx.x * epb;
  int e1 = min(E, e0 + epb);
  for (int e = e0 + tid; e < e1; e += 256) {
    int s = src[e];
    int d = dst[e];
    int p = atomicAdd(&cur[d >> NPB_SHIFT], 1);
    pairs[p] = ((unsigned long long)(unsigned)d << 32) | (unsigned)s;
  }
}

// ---------------------------------------------- bucketed CSR: pass B build
// one block per bucket: node histogram + scan + col staging in LDS,
// rp and col written coalesced.
__global__ __launch_bounds__(512) void kB_build(
    const unsigned long long* __restrict__ pairs, const int* __restrict__ off,
    int* __restrict__ rp, int* __restrict__ col, int N, int nbuk, int E) {
  __shared__ int cnt[NPB];
  __shared__ int exc[NPB];
  __shared__ int colstage[CAP];
  int tid = threadIdx.x;
  int b = blockIdx.x;
  int eb = off[(size_t)b * NBLK];
  int ee = off[(size_t)(b + 1) * NBLK];  // off[nbuk*NBLK] == E (scan3 wrote it)
  int m = ee - eb;

  cnt[tid] = 0;
  __syncthreads();
  for (int i = eb + tid; i < ee; i += NPB) {
    int d = (int)(pairs[i] >> 32);
    atomicAdd(&cnt[d & (NPB - 1)], 1);
  }
  __syncthreads();
  // block exclusive scan over cnt[0..NPB)
  exc[tid] = cnt[tid];
  __syncthreads();
  for (int o = 1; o < NPB; o <<= 1) {
    int v = (tid >= o) ? exc[tid - o] : 0;
    __syncthreads();
    exc[tid] += v;
    __syncthreads();
  }
  int myexc = exc[tid] - cnt[tid];
  int node = b * NPB + tid;
  if (node < N) rp[node] = eb + myexc;
  if (b == nbuk - 1 && tid == 0) rp[N] = E;
  __syncthreads();
  cnt[tid] = myexc;  // reuse as cursor
  __syncthreads();
  if (m <= CAP) {
    for (int i = eb + tid; i < ee; i += NPB) {
      unsigned long long pr = pairs[i];
      int d = (int)(pr >> 32);
      int s = (int)(pr & 0xffffffffu);
      int p = atomicAdd(&cnt[d & (NPB - 1)], 1);
      colstage[p] = s;
    }
    __syncthreads();
    for (int i = tid; i < m; i += NPB) col[eb + i] = colstage[i];
  } else {  // overflow fallback (statistically never taken)
    for (int i = eb + tid; i < ee; i += NPB) {
      unsigned long long pr = pairs[i];
      int d = (int)(pr >> 32);
      int s = (int)(pr & 0xffffffffu);
      int p = atomicAdd(&cnt[d & (NPB - 1)], 1);
      col[eb + p] = s;
    }
  }
}

// ---------------------------------------------------------- dtype conversion
__global__ void k_h2b(const float* __restrict__ h, unsigned short* __restrict__ hb,
                      int total8) {
  int i = blockIdx.x * 256 + threadIdx.x;
  if (i >= total8) return;
  const float4* h4 = (const float4*)h;
  float4 a = h4[(size_t)i * 2];
  float4 b = h4[(size_t)i * 2 + 1];
  u16x8 o;
  o[0] = f2bf(a.x); o[1] = f2bf(a.y); o[2] = f2bf(a.z); o[3] = f2bf(a.w);
  o[4] = f2bf(b.x); o[5] = f2bf(b.y); o[6] = f2bf(b.z); o[7] = f2bf(b.w);
  *(u16x8*)(hb + (size_t)i * 8) = o;
}

// Pack W[128k x 128col] fp32 into MFMA B-fragment order (bf16), 4 matrices.
__global__ void k_pack4(const float* __restrict__ W0, const float* __restrict__ W1,
                        const float* __restrict__ W2, const float* __restrict__ W3,
                        unsigned short* __restrict__ P0, unsigned short* __restrict__ P1,
                        unsigned short* __restrict__ P2, unsigned short* __restrict__ P3) {
  int gid = blockIdx.x * 256 + threadIdx.x;  // 0..65535
  int m = gid >> 14;
  int idx = gid & 16383;
  int j = idx & 7;
  int l = (idx >> 3) & 63;
  int kf = (idx >> 9) & 3;
  int ct = idx >> 11;
  int colc = ct * 16 + (l & 15);
  int k = kf * 32 + (l >> 4) * 8 + j;
  const float* W = (m == 0) ? W0 : (m == 1) ? W1 : (m == 2) ? W2 : W3;
  unsigned short* P = (m == 0) ? P0 : (m == 1) ? P1 : (m == 2) ? P2 : P3;
  P[idx] = f2bf(W[k * 128 + colc]);
}

// ------------------------------------------------------- fused MFMA GEMM
__global__ __launch_bounds__(256, 2) void k_gemm2(
    const unsigned short* __restrict__ hb, const unsigned short* __restrict__ WpS,
    const unsigned short* __restrict__ WpN, float* __restrict__ z,
    unsigned short* __restrict__ yb, int n) {
  const int l = threadIdx.x & 63;
  const int w = threadIdx.x >> 6;
  const int rowW = blockIdx.x * 128 + w * 32;
  const int cl = l & 15;
  const int cg = l >> 4;

  bf16x8 A[2][4];
#pragma unroll
  for (int rt = 0; rt < 2; ++rt) {
    int row = rowW + rt * 16 + cl;
#pragma unroll
    for (int kf = 0; kf < 4; ++kf) {
      if (row < n)
        A[rt][kf] = *(const bf16x8*)(hb + (size_t)row * 128 + kf * 32 + cg * 8);
      else
        A[rt][kf] = (bf16x8){0, 0, 0, 0, 0, 0, 0, 0};
    }
  }

  f32x4 accS[2][8], accN[2][8];
#pragma unroll
  for (int rt = 0; rt < 2; ++rt)
#pragma unroll
    for (int ct = 0; ct < 8; ++ct) {
      accS[rt][ct] = (f32x4){0.f, 0.f, 0.f, 0.f};
      accN[rt][ct] = (f32x4){0.f, 0.f, 0.f, 0.f};
    }

#pragma unroll
  for (int ct = 0; ct < 8; ++ct) {
    bf16x8 BS[4], BN[4];
#pragma unroll
    for (int kf = 0; kf < 4; ++kf) {
      BS[kf] = *(const bf16x8*)(WpS + ((ct * 4 + kf) * 64 + l) * 8);
      BN[kf] = *(const bf16x8*)(WpN + ((ct * 4 + kf) * 64 + l) * 8);
    }
#pragma unroll
    for (int rt = 0; rt < 2; ++rt)
#pragma unroll
      for (int kf = 0; kf < 4; ++kf) {
        accS[rt][ct] =
            __builtin_amdgcn_mfma_f32_16x16x32_bf16(A[rt][kf], BS[kf], accS[rt][ct], 0, 0, 0);
        accN[rt][ct] =
            __builtin_amdgcn_mfma_f32_16x16x32_bf16(A[rt][kf], BN[kf], accN[rt][ct], 0, 0, 0);
      }
  }

#pragma unroll
  for (int rt = 0; rt < 2; ++rt)
#pragma unroll
    for (int ct = 0; ct < 8; ++ct) {
#pragma unroll
      for (int r = 0; r < 4; ++r) {
        int row = rowW + rt * 16 + cg * 4 + r;
        if (row < n) {
          int colc = ct * 16 + cl;
          z[(size_t)row * 128 + colc] = accS[rt][ct][r];
          yb[(size_t)row * 128 + colc] = f2bf(accN[rt][ct][r]);
        }
      }
    }
}

// ------------------------------------------------- aggregation (pull, fused)
template <int OUTMODE>
__global__ __launch_bounds__(256, 8) void k_aggr2(
    const unsigned int* __restrict__ Y, const float* Z,
    const int* __restrict__ rp, const int* __restrict__ col,
    const float* __restrict__ bias, void* outp, int n) {
  int wid = (blockIdx.x * 256 + threadIdx.x) >> 6;
  int lane = threadIdx.x & 63;
  if (wid >= n) return;
  int s = rp[wid], e = rp[wid + 1];
  float ax = 0.f, ay = 0.f;
  int i = s;
  for (; i + 4 <= e; i += 4) {
    int c0 = col[i], c1 = col[i + 1], c2 = col[i + 2], c3 = col[i + 3];
    unsigned int v0 = Y[(size_t)c0 * 64 + lane];
    unsigned int v1 = Y[(size_t)c1 * 64 + lane];
    unsigned int v2 = Y[(size_t)c2 * 64 + lane];
    unsigned int v3 = Y[(size_t)c3 * 64 + lane];
    ax += bflo(v0) + bflo(v1) + bflo(v2) + bflo(v3);
    ay += bfhi(v0) + bfhi(v1) + bfhi(v2) + bfhi(v3);
  }
  for (; i < e; ++i) {
    unsigned int v = Y[(size_t)col[i] * 64 + lane];
    ax += bflo(v);
    ay += bfhi(v);
  }
  int deg = e - s;
  float scale = 1.0f / (float)(deg > 1 ? deg : 1);
  float2 zv = ((const float2*)Z)[(size_t)wid * 64 + lane];
  float2 bb = ((const float2*)bias)[lane];
  float ox = zv.x + ax * scale + bb.x;
  float oy = zv.y + ay * scale + bb.y;
  if (OUTMODE == 1) {
    ox = fmaxf(ox, 0.f);
    oy = fmaxf(oy, 0.f);
    unsigned int packed = (unsigned int)f2bf(ox) | ((unsigned int)f2bf(oy) << 16);
    ((unsigned int*)outp)[(size_t)wid * 64 + lane] = packed;
  } else {
    ((float2*)outp)[(size_t)wid * 64 + lane] = make_float2(ox, oy);
  }
}

// ---------------------------------------------------------------- pooling
__global__ void k_bounds(const int* __restrict__ gids, int* __restrict__ gs,
                         int n, int NG) {
  int g = threadIdx.x;
  if (g < NG) {
    int lo = 0, hi = n;
    while (lo < hi) {
      int m = (lo + hi) >> 1;
      if (gids[m] < g) lo = m + 1;
      else hi = m;
    }
    gs[g] = lo;
  } else if (g == NG) {
    gs[NG] = n;
  }
}

__global__ void k_pool(const float* __restrict__ H2, const int* __restrict__ gs,
                       float* __restrict__ gsum, int NG) {
  int g = blockIdx.x >> 2;
  int c = blockIdx.x & 3;
  int t = threadIdx.x;
  int s = gs[g], e = gs[g + 1];
  int cnt = e - s;
  int per = (cnt + 3) >> 2;
  int rs = s + c * per;
  int re = rs + per < e ? rs + per : e;
  float acc = 0.f;
  for (int r = rs; r < re; ++r) acc += H2[(size_t)r * DID + t];
  if (re > rs) atomicAdd(&gsum[g * DID + t], acc);
}

__global__ void k_head(const float* __restrict__ gsum,
                       const float* __restrict__ perm,
                       const float* __restrict__ Wc,
                       const float* __restrict__ bc,
                       const int* __restrict__ gs, float* __restrict__ out,
                       int NG) {
  int t = threadIdx.x;
  if (t >= NG * NCLS) return;
  int g = t >> 3, c = t & 7;
  int cnt = gs[g + 1] - gs[g];
  float inv = 1.0f / (float)(cnt > 1 ? cnt : 1);
  float acc = bc[c];
#pragma unroll 4
  for (int k = 0; k < DID; ++k)
    acc += gsum[g * DID + k] * inv * Wc[k * NCLS + c];
#pragma unroll 4
  for (int k = 0; k < DID; ++k)
    acc += perm[g * DID + k] * Wc[(DID + k) * NCLS + c];
  out[g * NCLS + c] = acc;
}

// ---------------------------------------------------------------- launch
extern "C" void kernel_launch(void* const* d_in, const int* in_sizes, int n_in,
                              void* d_out, int out_size, void* d_ws,
                              size_t ws_size, hipStream_t stream) {
  const float* h = (const float*)d_in[0];
  const float* perm = (const float*)d_in[1];
  const int* src = (const int*)d_in[2];
  const int* dst = (const int*)d_in[3];
  const int* gids = (const int*)d_in[4];
  const float* W1s = (const float*)d_in[5];
  const float* W1n = (const float*)d_in[6];
  const float* b1 = (const float*)d_in[7];
  const float* W2s = (const float*)d_in[8];
  const float* W2n = (const float*)d_in[9];
  const float* b2 = (const float*)d_in[10];
  const float* Wc = (const float*)d_in[11];
  const float* bc = (const float*)d_in[12];
  float* out = (float*)d_out;

  const int N = in_sizes[0] / DID;
  const int E = in_sizes[2];
  const int NG = in_sizes[1] / DID;
  const int nbuk = (N + NPB - 1) >> NPB_SHIFT;  // 196
  const int nscan = nbuk * NBLK;                // 100352

  char* w = (char*)d_ws;
  size_t off_ = 0;
  auto alloc = [&](size_t bytes) -> void* {
    off_ = (off_ + 511) & ~(size_t)511;
    void* p = w + off_;
    off_ += bytes;
    return p;
  };
  float* gsum = (float*)alloc((size_t)NG * DID * 4);
  size_t zbytes = off_;  // only gsum needs zeroing
  int* hist = (int*)alloc((size_t)nscan * 4);
  int* boff = (int*)alloc((size_t)(nscan + 1) * 4);
  int* part = (int*)alloc(1024 * 4);
  int* rp = (int*)alloc((size_t)(N + 1) * 4);
  int* gs = (int*)alloc((size_t)(NG + 1) * 4);
  int* col = (int*)alloc((size_t)E * 4);
  unsigned long long* pairs = (unsigned long long*)alloc((size_t)E * 8);
  unsigned short* hb = (unsigned short*)alloc((size_t)N * DID * 2);
  unsigned short* yb = (unsigned short*)alloc((size_t)N * DID * 2);
  float* z = (float*)alloc((size_t)N * DID * 4);
  unsigned short* Wp1s = (unsigned short*)alloc(128 * 128 * 2);
  unsigned short* Wp1n = (unsigned short*)alloc(128 * 128 * 2);
  unsigned short* Wp2s = (unsigned short*)alloc(128 * 128 * 2);
  unsigned short* Wp2n = (unsigned short*)alloc(128 * 128 * 2);

  hipMemsetAsync(d_ws, 0, zbytes, stream);

  const int nchunk = (nscan + 1023) / 1024;  // 98
  const int ngb = (N + 127) / 128;
  const int nagg = (N + 3) / 4;
  const int ncvt = ((N * DID / 8) + 255) / 256;

  // dtype prep
  k_h2b<<<ncvt, 256, 0, stream>>>(h, hb, N * DID / 8);
  k_pack4<<<256, 256, 0, stream>>>(W1s, W1n, W2s, W2n, Wp1s, Wp1n, Wp2s, Wp2n);

  // bucketed CSR by dst
  kB_hist<<<NBLK, 256, 0, stream>>>(dst, hist, E, nbuk);
  k_scan1<<<nchunk, 256, 0, stream>>>(hist, boff, part, nscan);
  k_scan2<<<1, 1024, 0, stream>>>(part, nchunk);
  k_scan3<<<nchunk, 256, 0, stream>>>(boff, part, nscan, E);  // boff[nscan]=E
  kB_scat<<<NBLK, 256, 0, stream>>>(src, dst, boff, pairs, E, nbuk);
  kB_build<<<nbuk, NPB, 0, stream>>>(pairs, boff, rp, col, N, nbuk, E);

  // layer 1: z=h@W1s (f32), yb=h@W1n (bf16); aggr -> h1 bf16 (into hb)
  k_gemm2<<<ngb, 256, 0, stream>>>(hb, Wp1s, Wp1n, z, yb, N);
  k_aggr2<1><<<nagg, 256, 0, stream>>>((const unsigned int*)yb, z, rp, col, b1,
                                       (void*)hb, N);

  // layer 2: z=h1@W2s, yb=h1@W2n; aggr -> h2 fp32 (in-place in z)
  k_gemm2<<<ngb, 256, 0, stream>>>(hb, Wp2s, Wp2n, z, yb, N);
  k_aggr2<0><<<nagg, 256, 0, stream>>>((const unsigned int*)yb, z, rp, col, b2,
                                       (void*)z, N);

  // readout
  k_bounds<<<1, 128, 0, stream>>>(gids, gs, N, NG);
  k_pool<<<NG * 4, 128, 0, stream>>>(z, gs, gsum, NG);
  k_head<<<1, 512, 0, stream>>>(gsum, perm, Wc, bc, gs, out, NG);
}

// Round 6
// 415.235 us; speedup vs baseline: 2.0456x; 1.2032x over previous
//
#include <hip/hip_runtime.h>

#define DID 128
#define NCLS 8
#define NPB 512        // nodes per bucket (power of 2)
#define NPB_SHIFT 9
#define NBLK 512       // blocks in edge-partition kernels
#define CAP 12288      // col staging capacity per bucket
#define PCHUNK 64      // pooling chunks per graph

typedef __attribute__((ext_vector_type(8))) short bf16x8;
typedef __attribute__((ext_vector_type(4))) float f32x4;
typedef __attribute__((ext_vector_type(8))) unsigned short u16x8;

static __device__ __forceinline__ unsigned short f2bf(float f) {
  union { float f; unsigned int u; } x;
  x.f = f;
  unsigned int r = (x.u + 0x7fffu + ((x.u >> 16) & 1u)) >> 16;  // RNE
  return (unsigned short)r;
}
static __device__ __forceinline__ float bfhi(unsigned int v) {
  union { unsigned int u; float f; } x;
  x.u = v & 0xffff0000u;
  return x.f;
}
static __device__ __forceinline__ float bflo(unsigned int v) {
  union { unsigned int u; float f; } x;
  x.u = v << 16;
  return x.f;
}

// ------------------------------------------------- bucketed CSR: pass A hist
__global__ __launch_bounds__(256) void kB_hist(const int* __restrict__ dst,
                                               int* __restrict__ hist, int E,
                                               int nbuk) {
  __shared__ int c[256];
  int tid = threadIdx.x;
  for (int i = tid; i < nbuk; i += 256) c[i] = 0;
  __syncthreads();
  int epb = (E + NBLK - 1) / NBLK;
  int e0 = blockIdx.x * epb;
  int e1 = min(E, e0 + epb);
  for (int e = e0 + tid; e < e1; e += 256)
    atomicAdd(&c[dst[e] >> NPB_SHIFT], 1);
  __syncthreads();
  for (int i = tid; i < nbuk; i += 256)
    hist[(size_t)i * NBLK + blockIdx.x] = c[i];
}

// generic exclusive scan chain (1024 elems / 256-thr block)
__global__ void k_scan1(const int* __restrict__ deg, int* __restrict__ rp,
                        int* __restrict__ part, int n) {
  __shared__ int sd[256];
  int t = threadIdx.x;
  int base = blockIdx.x * 1024 + t * 4;
  int v0 = (base + 0 < n) ? deg[base + 0] : 0;
  int v1 = (base + 1 < n) ? deg[base + 1] : 0;
  int v2 = (base + 2 < n) ? deg[base + 2] : 0;
  int v3 = (base + 3 < n) ? deg[base + 3] : 0;
  int ts = v0 + v1 + v2 + v3;
  sd[t] = ts;
  __syncthreads();
  for (int off = 1; off < 256; off <<= 1) {
    int x = 0;
    if (t >= off) x = sd[t - off];
    __syncthreads();
    if (t >= off) sd[t] += x;
    __syncthreads();
  }
  int excl = sd[t] - ts;
  if (base + 0 < n) rp[base + 0] = excl;
  if (base + 1 < n) rp[base + 1] = excl + v0;
  if (base + 2 < n) rp[base + 2] = excl + v0 + v1;
  if (base + 3 < n) rp[base + 3] = excl + v0 + v1 + v2;
  if (t == 255) part[blockIdx.x] = sd[255];
}

__global__ void k_scan2(int* __restrict__ part, int nblk) {
  __shared__ int sd[1024];
  int t = threadIdx.x;
  int v = (t < nblk) ? part[t] : 0;
  sd[t] = v;
  __syncthreads();
  for (int off = 1; off < 1024; off <<= 1) {
    int x = 0;
    if (t >= off) x = sd[t - off];
    __syncthreads();
    if (t >= off) sd[t] += x;
    __syncthreads();
  }
  if (t < nblk) part[t] = sd[t] - v;
}

__global__ void k_scan3(int* __restrict__ rp, const int* __restrict__ part,
                        int n, int E) {
  int t = threadIdx.x;
  int add = part[blockIdx.x];
  int base = blockIdx.x * 1024 + t * 4;
#pragma unroll
  for (int i = 0; i < 4; ++i)
    if (base + i < n) rp[base + i] += add;
  if (blockIdx.x == 0 && t == 0) rp[n] = E;
}

// -------------------------------------------- bucketed CSR: pass A scatter
__global__ __launch_bounds__(256) void kB_scat(const int* __restrict__ src,
                                               const int* __restrict__ dst,
                                               const int* __restrict__ off,
                                               unsigned long long* __restrict__ pairs,
                                               int E, int nbuk) {
  __shared__ int cur[256];
  int tid = threadIdx.x;
  for (int i = tid; i < nbuk; i += 256)
    cur[i] = off[(size_t)i * NBLK + blockIdx.x];
  __syncthreads();
  int epb = (E + NBLK - 1) / NBLK;
  int e0 = blockIdx.x * epb;
  int e1 = min(E, e0 + epb);
  for (int e = e0 + tid; e < e1; e += 256) {
    int s = src[e];
    int d = dst[e];
    int p = atomicAdd(&cur[d >> NPB_SHIFT], 1);
    pairs[p] = ((unsigned long long)(unsigned)d << 32) | (unsigned)s;
  }
}

// ---------------------------------------------- bucketed CSR: pass B build
__global__ __launch_bounds__(512) void kB_build(
    const unsigned long long* __restrict__ pairs, const int* __restrict__ off,
    int* __restrict__ rp, int* __restrict__ col, int N, int nbuk, int E) {
  __shared__ int cnt[NPB];
  __shared__ int exc[NPB];
  __shared__ int colstage[CAP];
  int tid = threadIdx.x;
  int b = blockIdx.x;
  int eb = off[(size_t)b * NBLK];
  int ee = off[(size_t)(b + 1) * NBLK];
  int m = ee - eb;

  cnt[tid] = 0;
  __syncthreads();
  for (int i = eb + tid; i < ee; i += NPB) {
    int d = (int)(pairs[i] >> 32);
    atomicAdd(&cnt[d & (NPB - 1)], 1);
  }
  __syncthreads();
  exc[tid] = cnt[tid];
  __syncthreads();
  for (int o = 1; o < NPB; o <<= 1) {
    int v = (tid >= o) ? exc[tid - o] : 0;
    __syncthreads();
    exc[tid] += v;
    __syncthreads();
  }
  int myexc = exc[tid] - cnt[tid];
  int node = b * NPB + tid;
  if (node < N) rp[node] = eb + myexc;
  if (b == nbuk - 1 && tid == 0) rp[N] = E;
  __syncthreads();
  cnt[tid] = myexc;  // reuse as cursor
  __syncthreads();
  if (m <= CAP) {
    for (int i = eb + tid; i < ee; i += NPB) {
      unsigned long long pr = pairs[i];
      int d = (int)(pr >> 32);
      int s = (int)(pr & 0xffffffffu);
      int p = atomicAdd(&cnt[d & (NPB - 1)], 1);
      colstage[p] = s;
    }
    __syncthreads();
    for (int i = tid; i < m; i += NPB) col[eb + i] = colstage[i];
  } else {
    for (int i = eb + tid; i < ee; i += NPB) {
      unsigned long long pr = pairs[i];
      int d = (int)(pr >> 32);
      int s = (int)(pr & 0xffffffffu);
      int p = atomicAdd(&cnt[d & (NPB - 1)], 1);
      col[eb + p] = s;
    }
  }
}

// ---------------------------------------------------------- dtype conversion
__global__ void k_h2b(const float* __restrict__ h, unsigned short* __restrict__ hb,
                      int total8) {
  int i = blockIdx.x * 256 + threadIdx.x;
  if (i >= total8) return;
  const float4* h4 = (const float4*)h;
  float4 a = h4[(size_t)i * 2];
  float4 b = h4[(size_t)i * 2 + 1];
  u16x8 o;
  o[0] = f2bf(a.x); o[1] = f2bf(a.y); o[2] = f2bf(a.z); o[3] = f2bf(a.w);
  o[4] = f2bf(b.x); o[5] = f2bf(b.y); o[6] = f2bf(b.z); o[7] = f2bf(b.w);
  *(u16x8*)(hb + (size_t)i * 8) = o;
}

// Pack W[128k x 128col] fp32 into MFMA B-fragment order (bf16), 4 matrices.
__global__ void k_pack4(const float* __restrict__ W0, const float* __restrict__ W1,
                        const float* __restrict__ W2, const float* __restrict__ W3,
                        unsigned short* __restrict__ P0, unsigned short* __restrict__ P1,
                        unsigned short* __restrict__ P2, unsigned short* __restrict__ P3) {
  int gid = blockIdx.x * 256 + threadIdx.x;  // 0..65535
  int m = gid >> 14;
  int idx = gid & 16383;
  int j = idx & 7;
  int l = (idx >> 3) & 63;
  int kf = (idx >> 9) & 3;
  int ct = idx >> 11;
  int colc = ct * 16 + (l & 15);
  int k = kf * 32 + (l >> 4) * 8 + j;
  const float* W = (m == 0) ? W0 : (m == 1) ? W1 : (m == 2) ? W2 : W3;
  unsigned short* P = (m == 0) ? P0 : (m == 1) ? P1 : (m == 2) ? P2 : P3;
  P[idx] = f2bf(W[k * 128 + colc]);
}

// ------------------------------------------------------- fused MFMA GEMM
__global__ __launch_bounds__(256, 2) void k_gemm2(
    const unsigned short* __restrict__ hb, const unsigned short* __restrict__ WpS,
    const unsigned short* __restrict__ WpN, float* __restrict__ z,
    unsigned short* __restrict__ yb, int n) {
  const int l = threadIdx.x & 63;
  const int w = threadIdx.x >> 6;
  const int rowW = blockIdx.x * 128 + w * 32;
  const int cl = l & 15;
  const int cg = l >> 4;

  bf16x8 A[2][4];
#pragma unroll
  for (int rt = 0; rt < 2; ++rt) {
    int row = rowW + rt * 16 + cl;
#pragma unroll
    for (int kf = 0; kf < 4; ++kf) {
      if (row < n)
        A[rt][kf] = *(const bf16x8*)(hb + (size_t)row * 128 + kf * 32 + cg * 8);
      else
        A[rt][kf] = (bf16x8){0, 0, 0, 0, 0, 0, 0, 0};
    }
  }

  f32x4 accS[2][8], accN[2][8];
#pragma unroll
  for (int rt = 0; rt < 2; ++rt)
#pragma unroll
    for (int ct = 0; ct < 8; ++ct) {
      accS[rt][ct] = (f32x4){0.f, 0.f, 0.f, 0.f};
      accN[rt][ct] = (f32x4){0.f, 0.f, 0.f, 0.f};
    }

#pragma unroll
  for (int ct = 0; ct < 8; ++ct) {
    bf16x8 BS[4], BN[4];
#pragma unroll
    for (int kf = 0; kf < 4; ++kf) {
      BS[kf] = *(const bf16x8*)(WpS + ((ct * 4 + kf) * 64 + l) * 8);
      BN[kf] = *(const bf16x8*)(WpN + ((ct * 4 + kf) * 64 + l) * 8);
    }
#pragma unroll
    for (int rt = 0; rt < 2; ++rt)
#pragma unroll
      for (int kf = 0; kf < 4; ++kf) {
        accS[rt][ct] =
            __builtin_amdgcn_mfma_f32_16x16x32_bf16(A[rt][kf], BS[kf], accS[rt][ct], 0, 0, 0);
        accN[rt][ct] =
            __builtin_amdgcn_mfma_f32_16x16x32_bf16(A[rt][kf], BN[kf], accN[rt][ct], 0, 0, 0);
      }
  }

#pragma unroll
  for (int rt = 0; rt < 2; ++rt)
#pragma unroll
    for (int ct = 0; ct < 8; ++ct) {
#pragma unroll
      for (int r = 0; r < 4; ++r) {
        int row = rowW + rt * 16 + cg * 4 + r;
        if (row < n) {
          int colc = ct * 16 + cl;
          z[(size_t)row * 128 + colc] = accS[rt][ct][r];
          yb[(size_t)row * 128 + colc] = f2bf(accN[rt][ct][r]);
        }
      }
    }
}

// ------------------------------------------------- aggregation (pull, fused)
// 8-deep gather unroll for memory-level parallelism (latency-bound kernel).
template <int OUTMODE>
__global__ __launch_bounds__(256, 8) void k_aggr2(
    const unsigned int* __restrict__ Y, const float* Z,
    const int* __restrict__ rp, const int* __restrict__ col,
    const float* __restrict__ bias, void* outp, int n) {
  int wid = (blockIdx.x * 256 + threadIdx.x) >> 6;
  int lane = threadIdx.x & 63;
  if (wid >= n) return;
  int s = rp[wid], e = rp[wid + 1];
  float ax = 0.f, ay = 0.f;
  int i = s;
  for (; i + 8 <= e; i += 8) {
    unsigned int v0 = Y[(size_t)col[i + 0] * 64 + lane];
    unsigned int v1 = Y[(size_t)col[i + 1] * 64 + lane];
    unsigned int v2 = Y[(size_t)col[i + 2] * 64 + lane];
    unsigned int v3 = Y[(size_t)col[i + 3] * 64 + lane];
    unsigned int v4 = Y[(size_t)col[i + 4] * 64 + lane];
    unsigned int v5 = Y[(size_t)col[i + 5] * 64 + lane];
    unsigned int v6 = Y[(size_t)col[i + 6] * 64 + lane];
    unsigned int v7 = Y[(size_t)col[i + 7] * 64 + lane];
    ax += bflo(v0) + bflo(v1) + bflo(v2) + bflo(v3) + bflo(v4) + bflo(v5) +
          bflo(v6) + bflo(v7);
    ay += bfhi(v0) + bfhi(v1) + bfhi(v2) + bfhi(v3) + bfhi(v4) + bfhi(v5) +
          bfhi(v6) + bfhi(v7);
  }
  for (; i + 4 <= e; i += 4) {
    unsigned int v0 = Y[(size_t)col[i + 0] * 64 + lane];
    unsigned int v1 = Y[(size_t)col[i + 1] * 64 + lane];
    unsigned int v2 = Y[(size_t)col[i + 2] * 64 + lane];
    unsigned int v3 = Y[(size_t)col[i + 3] * 64 + lane];
    ax += bflo(v0) + bflo(v1) + bflo(v2) + bflo(v3);
    ay += bfhi(v0) + bfhi(v1) + bfhi(v2) + bfhi(v3);
  }
  for (; i < e; ++i) {
    unsigned int v = Y[(size_t)col[i] * 64 + lane];
    ax += bflo(v);
    ay += bfhi(v);
  }
  int deg = e - s;
  float scale = 1.0f / (float)(deg > 1 ? deg : 1);
  float2 zv = ((const float2*)Z)[(size_t)wid * 64 + lane];
  float2 bb = ((const float2*)bias)[lane];
  float ox = zv.x + ax * scale + bb.x;
  float oy = zv.y + ay * scale + bb.y;
  if (OUTMODE == 1) {
    ox = fmaxf(ox, 0.f);
    oy = fmaxf(oy, 0.f);
    unsigned int packed = (unsigned int)f2bf(ox) | ((unsigned int)f2bf(oy) << 16);
    ((unsigned int*)outp)[(size_t)wid * 64 + lane] = packed;
  } else {
    ((float2*)outp)[(size_t)wid * 64 + lane] = make_float2(ox, oy);
  }
}

// ---------------------------------------------------------------- pooling
__global__ void k_bounds(const int* __restrict__ gids, int* __restrict__ gs,
                         int n, int NG) {
  int g = threadIdx.x;
  if (g < NG) {
    int lo = 0, hi = n;
    while (lo < hi) {
      int m = (lo + hi) >> 1;
      if (gids[m] < g) lo = m + 1;
      else hi = m;
    }
    gs[g] = lo;
  } else if (g == NG) {
    gs[NG] = n;
  }
}

// 4096 blocks x 256 thr: block covers 8 rows/iter (float4/lane),
// LDS tree-reduce -> 128 floats -> 128 atomicAdds per block.
__global__ __launch_bounds__(256) void k_pool(const float* __restrict__ H2,
                                              const int* __restrict__ gs,
                                              float* __restrict__ gsum, int NG) {
  int g = blockIdx.x / PCHUNK;
  int c = blockIdx.x % PCHUNK;
  int t = threadIdx.x;
  int s = gs[g], e = gs[g + 1];
  int cnt = e - s;
  int per = (cnt + PCHUNK - 1) / PCHUNK;
  int rs = s + c * per;
  int re = rs + per < e ? rs + per : e;
  if (rs >= re) return;  // uniform per block
  int rslot = t >> 5;    // 0..7
  int d4 = t & 31;       // float4 index within row
  const float4* H4 = (const float4*)H2;
  float4 acc = make_float4(0.f, 0.f, 0.f, 0.f);
  for (int r = rs + rslot; r < re; r += 8) {
    float4 v = H4[(size_t)r * 32 + d4];
    acc.x += v.x; acc.y += v.y; acc.z += v.z; acc.w += v.w;
  }
  __shared__ float4 sacc[256];
  sacc[t] = acc;
  __syncthreads();
#pragma unroll
  for (int o = 4; o >= 1; o >>= 1) {
    if (rslot < o) {
      float4 a = sacc[t];
      float4 b = sacc[t + o * 32];
      a.x += b.x; a.y += b.y; a.z += b.z; a.w += b.w;
      sacc[t] = a;
    }
    __syncthreads();
  }
  if (t < 32) {
    float4 a = sacc[t];
    atomicAdd(&gsum[g * DID + t * 4 + 0], a.x);
    atomicAdd(&gsum[g * DID + t * 4 + 1], a.y);
    atomicAdd(&gsum[g * DID + t * 4 + 2], a.z);
    atomicAdd(&gsum[g * DID + t * 4 + 3], a.w);
  }
}

__global__ void k_head(const float* __restrict__ gsum,
                       const float* __restrict__ perm,
                       const float* __restrict__ Wc,
                       const float* __restrict__ bc,
                       const int* __restrict__ gs, float* __restrict__ out,
                       int NG) {
  int t = threadIdx.x;
  if (t >= NG * NCLS) return;
  int g = t >> 3, c = t & 7;
  int cnt = gs[g + 1] - gs[g];
  float inv = 1.0f / (float)(cnt > 1 ? cnt : 1);
  float acc = bc[c];
#pragma unroll 4
  for (int k = 0; k < DID; ++k)
    acc += gsum[g * DID + k] * inv * Wc[k * NCLS + c];
#pragma unroll 4
  for (int k = 0; k < DID; ++k)
    acc += perm[g * DID + k] * Wc[(DID + k) * NCLS + c];
  out[g * NCLS + c] = acc;
}

// ---------------------------------------------------------------- launch
extern "C" void kernel_launch(void* const* d_in, const int* in_sizes, int n_in,
                              void* d_out, int out_size, void* d_ws,
                              size_t ws_size, hipStream_t stream) {
  const float* h = (const float*)d_in[0];
  const float* perm = (const float*)d_in[1];
  const int* src = (const int*)d_in[2];
  const int* dst = (const int*)d_in[3];
  const int* gids = (const int*)d_in[4];
  const float* W1s = (const float*)d_in[5];
  const float* W1n = (const float*)d_in[6];
  const float* b1 = (const float*)d_in[7];
  const float* W2s = (const float*)d_in[8];
  const float* W2n = (const float*)d_in[9];
  const float* b2 = (const float*)d_in[10];
  const float* Wc = (const float*)d_in[11];
  const float* bc = (const float*)d_in[12];
  float* out = (float*)d_out;

  const int N = in_sizes[0] / DID;
  const int E = in_sizes[2];
  const int NG = in_sizes[1] / DID;
  const int nbuk = (N + NPB - 1) >> NPB_SHIFT;
  const int nscan = nbuk * NBLK;

  char* w = (char*)d_ws;
  size_t off_ = 0;
  auto alloc = [&](size_t bytes) -> void* {
    off_ = (off_ + 511) & ~(size_t)511;
    void* p = w + off_;
    off_ += bytes;
    return p;
  };
  float* gsum = (float*)alloc((size_t)NG * DID * 4);
  size_t zbytes = off_;  // only gsum needs zeroing
  int* hist = (int*)alloc((size_t)nscan * 4);
  int* boff = (int*)alloc((size_t)(nscan + 1) * 4);
  int* part = (int*)alloc(1024 * 4);
  int* rp = (int*)alloc((size_t)(N + 1) * 4);
  int* gs = (int*)alloc((size_t)(NG + 1) * 4);
  int* col = (int*)alloc((size_t)E * 4);
  unsigned long long* pairs = (unsigned long long*)alloc((size_t)E * 8);
  unsigned short* hb = (unsigned short*)alloc((size_t)N * DID * 2);
  unsigned short* yb = (unsigned short*)alloc((size_t)N * DID * 2);
  float* z = (float*)alloc((size_t)N * DID * 4);
  unsigned short* Wp1s = (unsigned short*)alloc(128 * 128 * 2);
  unsigned short* Wp1n = (unsigned short*)alloc(128 * 128 * 2);
  unsigned short* Wp2s = (unsigned short*)alloc(128 * 128 * 2);
  unsigned short* Wp2n = (unsigned short*)alloc(128 * 128 * 2);

  hipMemsetAsync(d_ws, 0, zbytes, stream);

  const int nchunk = (nscan + 1023) / 1024;
  const int ngb = (N + 127) / 128;
  const int nagg = (N + 3) / 4;
  const int ncvt = ((N * DID / 8) + 255) / 256;

  // dtype prep
  k_h2b<<<ncvt, 256, 0, stream>>>(h, hb, N * DID / 8);
  k_pack4<<<256, 256, 0, stream>>>(W1s, W1n, W2s, W2n, Wp1s, Wp1n, Wp2s, Wp2n);

  // bucketed CSR by dst
  kB_hist<<<NBLK, 256, 0, stream>>>(dst, hist, E, nbuk);
  k_scan1<<<nchunk, 256, 0, stream>>>(hist, boff, part, nscan);
  k_scan2<<<1, 1024, 0, stream>>>(part, nchunk);
  k_scan3<<<nchunk, 256, 0, stream>>>(boff, part, nscan, E);
  kB_scat<<<NBLK, 256, 0, stream>>>(src, dst, boff, pairs, E, nbuk);
  kB_build<<<nbuk, NPB, 0, stream>>>(pairs, boff, rp, col, N, nbuk, E);

  // layer 1: z=h@W1s (f32), yb=h@W1n (bf16); aggr -> h1 bf16 (into hb)
  k_gemm2<<<ngb, 256, 0, stream>>>(hb, Wp1s, Wp1n, z, yb, N);
  k_aggr2<1><<<nagg, 256, 0, stream>>>((const unsigned int*)yb, z, rp, col, b1,
                                       (void*)hb, N);

  // layer 2: z=h1@W2s, yb=h1@W2n; aggr -> h2 fp32 (in-place in z)
  k_gemm2<<<ngb, 256, 0, stream>>>(hb, Wp2s, Wp2n, z, yb, N);
  k_aggr2<0><<<nagg, 256, 0, stream>>>((const unsigned int*)yb, z, rp, col, b2,
                                       (void*)z, N);

  // readout
  k_bounds<<<1, 128, 0, stream>>>(gids, gs, N, NG);
  k_pool<<<NG * PCHUNK, 256, 0, stream>>>(z, gs, gsum, NG);
  k_head<<<1, 512, 0, stream>>>(gsum, perm, Wc, bc, gs, out, NG);
}